// Round 9
// baseline (577.132 us; speedup 1.0000x reference)
//
#include <hip/hip_runtime.h>
#include <hip/hip_bf16.h>
#include <cstdint>
#include <cstddef>

#define T_TOK 1024
#define H_DIM 2048
#define NH 32
#define HS 64
#define TH (T_TOK * H_DIM)
#define HH (H_DIM * H_DIM)

using short8 = __attribute__((ext_vector_type(8))) short;
using f32x4  = __attribute__((ext_vector_type(4))) float;
using i32x4  = __attribute__((ext_vector_type(4))) int;
typedef __hip_bfloat16 bf16;

__device__ __forceinline__ float sigmoidf_(float x) { return 1.0f / (1.0f + expf(-x)); }

__device__ __forceinline__ float wsum64(float v) {
#pragma unroll
    for (int m = 32; m; m >>= 1) v += __shfl_xor(v, m, 64);
    return v;
}

// DPP sum over aligned 16-lane groups — pure VALU, no DS ops.
__device__ __forceinline__ float dpp_add16(float x) {
    int t;
    t = __builtin_amdgcn_update_dpp(0, __float_as_int(x), 0xB1, 0xF, 0xF, true);
    x += __int_as_float(t);
    t = __builtin_amdgcn_update_dpp(0, __float_as_int(x), 0x4E, 0xF, 0xF, true);
    x += __int_as_float(t);
    t = __builtin_amdgcn_update_dpp(0, __float_as_int(x), 0x141, 0xF, 0xF, true);
    x += __int_as_float(t);
    t = __builtin_amdgcn_update_dpp(0, __float_as_int(x), 0x140, 0xF, 0xF, true);
    x += __int_as_float(t);
    return x;
}

// ---------------- cast big weights fp32 -> bf16 ----------------
struct CastPar { const float* src[4]; bf16* dst[4]; };
__global__ __launch_bounds__(256) void castw_kernel(CastPar p) {
    int z = blockIdx.z;
    const float4* s = (const float4*)p.src[z];
    bf16* d = p.dst[z];
    int i = blockIdx.x * 256 + threadIdx.x;
    float4 v = s[i];
    int b = i * 4;
    d[b + 0] = __float2bfloat16(v.x);
    d[b + 1] = __float2bfloat16(v.y);
    d[b + 2] = __float2bfloat16(v.z);
    d[b + 3] = __float2bfloat16(v.w);
}

// ---------------- transpose + cast small weights ----------------
struct TPar { const float* src[8]; bf16* dst[8]; int R[8]; int C[8]; };
__global__ __launch_bounds__(256) void transpose_kernel(TPar p) {
    int z = blockIdx.z;
    int R = p.R[z], C = p.C[z];
    int e = blockIdx.x * 256 + threadIdx.x;
    if (e >= R * C) return;
    int r = e / C, c = e % C;
    p.dst[z][(size_t)c * R + r] = __float2bfloat16(p.src[z][e]);
}

// ---------------- LayerNorm (ln1) ----------------
__global__ __launch_bounds__(256) void ln_kernel(const float* __restrict__ x,
                                                 const float* __restrict__ w,
                                                 const float* __restrict__ b,
                                                 float* __restrict__ xn,
                                                 float* __restrict__ s1out) {
    int t = blockIdx.x, tid = threadIdx.x;
    const float* xt = x + (size_t)t * H_DIM;
    float v[8]; float s = 0.f, s2 = 0.f;
#pragma unroll
    for (int e = 0; e < 8; e++) { v[e] = xt[tid + 256 * e]; s += v[e]; s2 += v[e] * v[e]; }
    s = wsum64(s); s2 = wsum64(s2);
    __shared__ float ls[8];
    int wid = tid >> 6, ln = tid & 63;
    if (ln == 0) { ls[wid] = s; ls[4 + wid] = s2; }
    __syncthreads();
    s = ls[0] + ls[1] + ls[2] + ls[3];
    s2 = ls[4] + ls[5] + ls[6] + ls[7];
    float mu = s * (1.f / H_DIM);
    float var = s2 * (1.f / H_DIM) - mu * mu;
    float inv = rsqrtf(var + 1e-5f);
#pragma unroll
    for (int e = 0; e < 8; e++) {
        int h = tid + 256 * e;
        float o = (v[e] - mu) * inv * w[h] + b[h];
        xn[(size_t)t * H_DIM + h] = o;
        if (t == T_TOK - 1) s1out[h] = o;
    }
}

// ---------------- token-shift mixes ----------------
struct MixPar { const float* xn; const float* state1; const float* mv[6]; bf16* out[6]; };
__global__ __launch_bounds__(256) void mix_kernel(MixPar p) {
    int t = blockIdx.x, tid = threadIdx.x;
#pragma unroll
    for (int e = 0; e < 8; e++) {
        int h = tid + 256 * e;
        size_t idx = (size_t)t * H_DIM + h;
        float cur = p.xn[idx];
        float prev = (t == 0) ? p.state1[h] : p.xn[idx - H_DIM];
        float sx = prev - cur;
#pragma unroll
        for (int q = 0; q < 6; q++)
            p.out[q][idx] = __float2bfloat16(cur + p.mv[q][h] * sx);
    }
}

// ======== async global->LDS helpers (size 16 ONLY — HW-verified path) ========
typedef const __attribute__((address_space(1))) uint32_t* gp1_t;
typedef __attribute__((address_space(3))) uint32_t* lp3_t;
__device__ __forceinline__ void async16(const bf16* g, short* l) {
    __builtin_amdgcn_global_load_lds((gp1_t)g, (lp3_t)l, 16, 0, 0);
}
__device__ __forceinline__ void async16v(const void* g, void* l) {
    __builtin_amdgcn_global_load_lds((gp1_t)g, (lp3_t)l, 16, 0, 0);
}

// ======== big GEMM: 4-stage ring global_load_lds pipeline (vmcnt(12)) ========
struct BGPar { const bf16* X[4]; const bf16* W[4]; float* out[4]; const float* resid[4]; };
__global__ __launch_bounds__(256) void bgemm_kernel(BGPar p) {
    int z = blockIdx.z;
    const bf16* __restrict__ X = p.X[z];
    const bf16* __restrict__ W = p.W[z];
    float* __restrict__ out = p.out[z];
    const float* __restrict__ resid = p.resid[z];

    __shared__ short As[4][128 * 32];   // 4 stages x 8 KB
    __shared__ short Bs[4][128 * 32];   // 4 stages x 8 KB  (64 KB total)

    int m0 = blockIdx.y * 128, n0 = blockIdx.x * 128;
    int tid = threadIdx.x, lane = tid & 63, wv = tid >> 6;
    int m_off = (wv >> 1) * 64, n_off = (wv & 1) * 64;
    int lr = lane & 15, lq = lane >> 4;

    int srow = lane >> 2;
    int scol = (lane & 3) * 8;
    const bf16* Ag0 = X + (size_t)(m0 + wv * 32 + srow) * 2048 + scol;
    const bf16* Ag1 = Ag0 + (size_t)16 * 2048;
    const bf16* Bg0 = W + (size_t)(n0 + wv * 32 + srow) * 2048 + scol;
    const bf16* Bg1 = Bg0 + (size_t)16 * 2048;

    // issue stage: tile `at` (address), ring buffer `nb`
    auto issue = [&](int at, int nb) {
        int kk = at * 32;
        async16(Ag0 + kk, &As[nb][(wv * 32) * 32]);
        async16(Ag1 + kk, &As[nb][(wv * 32 + 16) * 32]);
        async16(Bg0 + kk, &Bs[nb][(wv * 32) * 32]);
        async16(Bg1 + kk, &Bs[nb][(wv * 32 + 16) * 32]);
    };

    f32x4 acc[4][4];
#pragma unroll
    for (int a = 0; a < 4; a++)
#pragma unroll
        for (int b = 0; b < 4; b++)
#pragma unroll
            for (int r = 0; r < 4; r++) acc[a][b][r] = 0.f;

    issue(0, 0); issue(1, 1); issue(2, 2);

    for (int it = 0; it < 64; it++) {
        int nt = it + 3;
        int at = nt > 63 ? 63 : nt;      // clamp address; redundant tail loads keep vmcnt uniform
        issue(at, nt & 3);               // buf (it-1)&3: consumed last iter, safe after trailing barrier
        asm volatile("s_waitcnt vmcnt(12)" ::: "memory");  // stage `it` landed; 3 stages stay in flight
        asm volatile("s_barrier" ::: "memory");            // all waves' stage-it data in LDS
        int buf = it & 3;
        short8 af[4], bfr[4];
#pragma unroll
        for (int mi = 0; mi < 4; mi++)
            af[mi] = *(const short8*)&As[buf][(m_off + mi * 16 + lr) * 32 + lq * 8];
#pragma unroll
        for (int ni = 0; ni < 4; ni++)
            bfr[ni] = *(const short8*)&Bs[buf][(n_off + ni * 16 + lr) * 32 + lq * 8];
#pragma unroll
        for (int mi = 0; mi < 4; mi++)
#pragma unroll
            for (int ni = 0; ni < 4; ni++)
                acc[mi][ni] = __builtin_amdgcn_mfma_f32_16x16x32_bf16(af[mi], bfr[ni], acc[mi][ni], 0, 0, 0);
        asm volatile("s_barrier" ::: "memory");            // buf free for overwrite next iter
    }
    asm volatile("s_waitcnt vmcnt(0)" ::: "memory");       // drain redundant tail loads

#pragma unroll
    for (int mi = 0; mi < 4; mi++)
#pragma unroll
        for (int ni = 0; ni < 4; ni++)
#pragma unroll
            for (int r = 0; r < 4; r++) {
                int rowg = m0 + m_off + mi * 16 + lq * 4 + r;
                int colg = n0 + n_off + ni * 16 + lr;
                size_t o = (size_t)rowg * 2048 + colg;
                float v = acc[mi][ni][r];
                if (resid) v += resid[o];
                out[o] = v;
            }
}

// ---------------- generic small-GEMM ----------------
#define BM 128
#define BN 128
#define BK 32
#define LDK 40

__device__ __forceinline__ void gemm_core(const bf16* __restrict__ X, const bf16* __restrict__ W,
                                          int M, int N, int K, int act,
                                          const float* __restrict__ bias,
                                          float* __restrict__ outF, bf16* __restrict__ outB) {
    __shared__ short As[BM * LDK];
    __shared__ short Bs[BN * LDK];
    int m0 = blockIdx.y * BM, n0 = blockIdx.x * BN;
    if (n0 >= N) return;
    int tid = threadIdx.x;
    int lane = tid & 63, wid = tid >> 6;
    int m_off = (wid >> 1) * 64, n_off = (wid & 1) * 64;
    int lr = lane & 15, lq = lane >> 4;

    f32x4 acc[4][4];
#pragma unroll
    for (int a = 0; a < 4; a++)
#pragma unroll
        for (int b = 0; b < 4; b++)
#pragma unroll
            for (int r = 0; r < 4; r++) acc[a][b][r] = 0.f;

    for (int k0 = 0; k0 < K; k0 += BK) {
#pragma unroll
        for (int it = 0; it < 2; it++) {
            int c = tid + it * 256;
            int r = c >> 2;
            int cc = (c & 3) * 8;
            uint4 va = *(const uint4*)(X + (size_t)(m0 + r) * K + k0 + cc);
            *(uint4*)&As[r * LDK + cc] = va;
            uint4 vb;
            if (n0 + r < N) vb = *(const uint4*)(W + (size_t)(n0 + r) * K + k0 + cc);
            else            vb = make_uint4(0u, 0u, 0u, 0u);
            *(uint4*)&Bs[r * LDK + cc] = vb;
        }
        __syncthreads();
        short8 af[4], bfr[4];
#pragma unroll
        for (int mi = 0; mi < 4; mi++)
            af[mi] = *(const short8*)&As[(m_off + mi * 16 + lr) * LDK + lq * 8];
#pragma unroll
        for (int ni = 0; ni < 4; ni++)
            bfr[ni] = *(const short8*)&Bs[(n_off + ni * 16 + lr) * LDK + lq * 8];
#pragma unroll
        for (int mi = 0; mi < 4; mi++)
#pragma unroll
            for (int ni = 0; ni < 4; ni++)
                acc[mi][ni] = __builtin_amdgcn_mfma_f32_16x16x32_bf16(af[mi], bfr[ni], acc[mi][ni], 0, 0, 0);
        __syncthreads();
    }
#pragma unroll
    for (int mi = 0; mi < 4; mi++)
#pragma unroll
        for (int ni = 0; ni < 4; ni++)
#pragma unroll
            for (int r = 0; r < 4; r++) {
                int rowg = m0 + m_off + mi * 16 + lq * 4 + r;
                int colg = n0 + n_off + ni * 16 + lr;
                if (colg < N) {
                    float v = acc[mi][ni][r];
                    if (bias) v += bias[colg];
                    if (act == 1) v = sigmoidf_(v);
                    else if (act == 2) v = tanhf(v);
                    size_t o = (size_t)rowg * N + colg;
                    if (outF) outF[o] = v;
                    else      outB[o] = __float2bfloat16(v);
                }
            }
}

struct GPar {
    const bf16* X[4]; const bf16* W[4];
    float* outF[4]; bf16* outB[4];
    const float* bias[4];
    int N[4]; int K[4]; int act[4]; int M;
};
__global__ __launch_bounds__(256) void gemm_z_kernel(GPar p) {
    int z = blockIdx.z;
    gemm_core(p.X[z], p.W[z], p.M, p.N[z], p.K[z], p.act[z], p.bias[z], p.outF[z], p.outB[z]);
}

// ---------------- elementwise prep for the scan ----------------
// Writes, per (h,t), ONE contiguous 768 B record at PKW + (h*T + t)*768:
//   bytes [0,256):   w   fp32[64]                  (precision-critical decay)
//   bytes [256,512): a|b bf16, per jb 16B = {a0..a3, b0..b3}
//   bytes [512,768): k|r bf16, per jb 16B = {k0..k3, r0..r3}
// [h][t] order makes an 8-step chunk 6144 CONTIGUOUS bytes = 6 x async16.
// v goes to VH[h][t][64] fp32 (per-head contiguous: 8-step chunk = 2 async16).
// v also still written to vb for post_kernel.
__global__ __launch_bounds__(64) void prep_kernel(float* __restrict__ k_io, float* __restrict__ v_io,
                                                  const float* __restrict__ v_first,
                                                  const float* __restrict__ vres,
                                                  const float* __restrict__ w_in,
                                                  const float* __restrict__ a_io,
                                                  const float* __restrict__ r_in,
                                                  char* __restrict__ pkw,
                                                  float* __restrict__ vh,
                                                  const float* __restrict__ k_k,
                                                  const float* __restrict__ k_a,
                                                  const float* __restrict__ w0) {
    int h = blockIdx.x, t = blockIdx.y, i = threadIdx.x;
    int hi = h * HS + i;
    size_t idx = (size_t)t * H_DIM + hi;
    float kf = k_io[idx];
    float kk = kf * k_k[hi];
    float ss = wsum64(kk * kk);
    float kkn = kk / (sqrtf(ss) + 1e-12f);
    float a = a_io[idx];
    float knew = kf * (1.f + (a - 1.f) * k_a[hi]);
    k_io[idx] = knew;                       // fp32 k kept for post_kernel
    float vv = v_io[idx];
    float vnew = vv + (v_first[idx] - vv) * vres[idx];
    v_io[idx] = vnew;
    float wfin = expf(-0.606531f * sigmoidf_(w0[hi] + w_in[idx]));

    char* rec = pkw + ((size_t)h * T_TOK + t) * 768;
    ((float*)rec)[i] = wfin;
    int sub = (i >> 2) * 8 + (i & 3);
    bf16* ab = (bf16*)(rec + 256);
    bf16* kr = (bf16*)(rec + 512);
    ab[sub]     = __float2bfloat16(-kkn);       // a_seq
    ab[sub + 4] = __float2bfloat16(kkn * a);    // b_seq
    kr[sub]     = __float2bfloat16(knew);       // k
    kr[sub + 4] = __float2bfloat16(r_in[idx]);  // r

    vh[((size_t)h * T_TOK + t) * HS + i] = vnew;
}

// ---------------- WKV7 scan: producer/consumer LDS ring ----------------
// r8 (WIN, 148->132us): one-step LDS prefetch + tree reduction. Remaining
// step cost (~310cy): VALU issue (~88cy) + dependent stalls at 1 wave/SIMD.
// This round: hoist the bf16 UNPACK and the v*k product into the prefetch
// stage (rotation registers carry ready floats), and prefetch ACROSS the
// chunk barrier (j=7 prefetches step 0 of slot (c+1)&3). To guarantee that
// slot at barrier c, producer wait tightens vmcnt(16) -> vmcnt(8) (chunks
// c AND c+1 landed). Slot ledger: producer writes (c+3)&3; consumers read
// c&3 and (c+1)&3 — disjoint. Compute step consumes only pre-unpacked regs:
//   S*=w -> sa tree -> dpp16 -> S = fmaf(sa,b,S+vk) ; o-tree off-chain.
#define SC_CH 8          // steps per chunk
#define SC_SLOT 8192     // 6144 pkw + 2048 v
__global__ __launch_bounds__(192) void scan_kernel(const char* __restrict__ pkw,
                                                   const float* __restrict__ vh,
                                                   const float* __restrict__ s2in,
                                                   float* __restrict__ y,
                                                   float* __restrict__ s2out) {
    __shared__ char smem[4 * SC_SLOT];
    int h = blockIdx.x, bq = blockIdx.y;
    int wid = threadIdx.x >> 6;          // 0,1 = consumers; 2 = producer
    int lane = threadIdx.x & 63;
    int hb = h * HS;

    // consumer-side geometry
    int q = bq * 2 + wid;                // valid for wid<2
    int il = lane >> 4, jb = lane & 15;
    int row = q * 4 + il;

    float S[4] = {0.f, 0.f, 0.f, 0.f};
    if (wid < 2) {
        const float* s0 = s2in + (size_t)h * HS * HS + (size_t)row * HS + (size_t)jb * 4;
        float4 t0 = *(const float4*)s0;
        S[0] = t0.x; S[1] = t0.y; S[2] = t0.z; S[3] = t0.w;
    }

    // producer: issue one chunk (8 steps, 8 x async16) into ring slot c&3
    auto issue_chunk = [&](int c) {
        char* lb = smem + (size_t)(c & 3) * SC_SLOT;
        const char* gp = pkw + ((size_t)h * T_TOK + (size_t)c * SC_CH) * 768;
        const char* gv = (const char*)vh + ((size_t)h * T_TOK + (size_t)c * SC_CH) * 256;
#pragma unroll
        for (int i = 0; i < 6; i++)
            async16v(gp + i * 1024 + lane * 16, lb + i * 1024);
#pragma unroll
        for (int i = 0; i < 2; i++)
            async16v(gv + i * 1024 + lane * 16, lb + 6144 + i * 1024);
    };

    if (wid == 2) {
        issue_chunk(0); issue_chunk(1); issue_chunk(2);   // 24 ops in flight
    }

    // rotation registers: pre-unpacked operands for the CURRENT step
    float wA[4], aA[4], bA[4], vkA[4], rA[4];

    // load + unpack one step's operands from LDS (rec = 768B record base,
    // vbase = v array base for this step)
    auto unpack = [&](const char* rec, const char* vbase,
                      float* w_, float* a_, float* b_, float* vk_, float* r_) {
        f32x4 wv = *(const f32x4*)(rec + jb * 16);
        i32x4 q0 = *(const i32x4*)(rec + 256 + jb * 16);
        i32x4 q1 = *(const i32x4*)(rec + 512 + jb * 16);
        float vv = *(const float*)(vbase + row * 4);
        uint32_t u;
        float kf[4];
        u = (uint32_t)q0[0]; a_[0] = __uint_as_float(u << 16); a_[1] = __uint_as_float(u & 0xffff0000u);
        u = (uint32_t)q0[1]; a_[2] = __uint_as_float(u << 16); a_[3] = __uint_as_float(u & 0xffff0000u);
        u = (uint32_t)q0[2]; b_[0] = __uint_as_float(u << 16); b_[1] = __uint_as_float(u & 0xffff0000u);
        u = (uint32_t)q0[3]; b_[2] = __uint_as_float(u << 16); b_[3] = __uint_as_float(u & 0xffff0000u);
        u = (uint32_t)q1[0]; kf[0] = __uint_as_float(u << 16); kf[1] = __uint_as_float(u & 0xffff0000u);
        u = (uint32_t)q1[1]; kf[2] = __uint_as_float(u << 16); kf[3] = __uint_as_float(u & 0xffff0000u);
        u = (uint32_t)q1[2]; r_[0] = __uint_as_float(u << 16); r_[1] = __uint_as_float(u & 0xffff0000u);
        u = (uint32_t)q1[3]; r_[2] = __uint_as_float(u << 16); r_[3] = __uint_as_float(u & 0xffff0000u);
#pragma unroll
        for (int e = 0; e < 4; e++) { w_[e] = wv[e]; vk_[e] = vv * kf[e]; }
    };

    for (int c = 0; c < T_TOK / SC_CH; c++) {
        if (wid == 2)
            asm volatile("s_waitcnt vmcnt(8)" ::: "memory");   // chunks c AND c+1 landed
        asm volatile("" ::: "memory");
        __builtin_amdgcn_s_barrier();
        asm volatile("" ::: "memory");
        if (wid == 2) {
            int cn = c + 3;
            if (cn > T_TOK / SC_CH - 1) cn = T_TOK / SC_CH - 1;  // redundant tail (identical data) keeps vmcnt uniform
            issue_chunk(cn);
        } else {
            const char* lb = smem + (size_t)(c & 3) * SC_SLOT;
            if (c == 0)
                unpack(lb, lb + 6144, wA, aA, bA, vkA, rA);
#pragma unroll
            for (int j = 0; j < SC_CH; j++) {
                // prefetch + unpack NEXT step (within chunk, or step 0 of
                // slot (c+1)&3 — guaranteed landed by the vmcnt(8) wait)
                float wB[4], aB[4], bB[4], vkB[4], rB[4];
                if (j + 1 < SC_CH) {
                    unpack(lb + (j + 1) * 768, lb + 6144 + (j + 1) * 256,
                           wB, aB, bB, vkB, rB);
                } else {
                    const char* ln = smem + (size_t)((c + 1) & 3) * SC_SLOT;
                    unpack(ln, ln + 6144, wB, aB, bB, vkB, rB);
                }
                int t = c * SC_CH + j;
#pragma unroll
                for (int e = 0; e < 4; e++) S[e] *= wA[e];
                float sa = fmaf(S[0], aA[0], S[1] * aA[1]) + fmaf(S[2], aA[2], S[3] * aA[3]);
                sa = dpp_add16(sa);
#pragma unroll
                for (int e = 0; e < 4; e++)
                    S[e] = fmaf(sa, bA[e], S[e] + vkA[e]);
                float o = fmaf(S[0], rA[0], S[1] * rA[1]) + fmaf(S[2], rA[2], S[3] * rA[3]);
                o = dpp_add16(o);
                y[(size_t)t * H_DIM + hb + row] = o;   // 16 lanes, same addr/value
#pragma unroll
                for (int e = 0; e < 4; e++) {
                    wA[e] = wB[e]; aA[e] = aB[e]; bA[e] = bB[e];
                    vkA[e] = vkB[e]; rA[e] = rB[e];
                }
            }
        }
    }
    if (wid == 2) {
        asm volatile("s_waitcnt vmcnt(0)" ::: "memory");   // drain redundant tail before exit
    } else {
        float* so = s2out + (size_t)h * HS * HS + (size_t)row * HS + (size_t)jb * 4;
        float4 t0;
        t0.x = S[0]; t0.y = S[1]; t0.z = S[2]; t0.w = S[3];
        *(float4*)so = t0;
    }
}

// ---------------- groupnorm + bonus + gate -> bf16 ----------------
__global__ __launch_bounds__(64) void post_kernel(const float* __restrict__ y,
                                                  const float* __restrict__ r_s,
                                                  const float* __restrict__ k_s,
                                                  const float* __restrict__ v_s,
                                                  const float* __restrict__ g_s,
                                                  const float* __restrict__ r_k,
                                                  const float* __restrict__ lnw,
                                                  const float* __restrict__ lnb,
                                                  bf16* __restrict__ ybig) {
    int h = blockIdx.x, t = blockIdx.y, i = threadIdx.x;
    int hi = h * HS + i;
    size_t idx = (size_t)t * H_DIM + hi;
    float yv = y[idx];
    float mu = wsum64(yv) * (1.f / HS);
    float d = yv - mu;
    float var = wsum64(d * d) * (1.f / HS);
    float yn = d * rsqrtf(var + 0.00064f);
    float bd = wsum64(r_s[idx] * k_s[idx] * r_k[hi]);
    float val = (yn * lnw[hi] + lnb[hi] + bd * v_s[idx]) * g_s[idx];
    ybig[idx] = __float2bfloat16(val);
}

// ---------------- launcher ----------------
extern "C" void kernel_launch(void* const* d_in, const int* in_sizes, int n_in,
                              void* d_out, int out_size, void* d_ws, size_t ws_size,
                              hipStream_t stream) {
    const float* x      = (const float*)d_in[0];
    const float* state1 = (const float*)d_in[1];
    const float* state2 = (const float*)d_in[2];
    const float* vfirst = (const float*)d_in[3];
    const float* x_r = (const float*)d_in[4];
    const float* x_w = (const float*)d_in[5];
    const float* x_k = (const float*)d_in[6];
    const float* x_v = (const float*)d_in[7];
    const float* x_a = (const float*)d_in[8];
    const float* x_g = (const float*)d_in[9];
    const float* W_r = (const float*)d_in[10];
    const float* W_k = (const float*)d_in[11];
    const float* W_v = (const float*)d_in[12];
    const float* W_o = (const float*)d_in[13];
    const float* w0 = (const float*)d_in[14];
    const float* w1 = (const float*)d_in[15];
    const float* w2 = (const float*)d_in[16];
    const float* a0 = (const float*)d_in[17];
    const float* a1 = (const float*)d_in[18];
    const float* a2 = (const float*)d_in[19];
    const float* v0 = (const float*)d_in[20];
    const float* v1 = (const float*)d_in[21];
    const float* v2 = (const float*)d_in[22];
    const float* g1 = (const float*)d_in[23];
    const float* g2 = (const float*)d_in[24];
    const float* k_k = (const float*)d_in[25];
    const float* k_a = (const float*)d_in[26];
    const float* r_k = (const float*)d_in[27];
    const float* ln_x_w = (const float*)d_in[28];
    const float* ln_x_b = (const float*)d_in[29];
    const float* ln1_w = (const float*)d_in[30];
    const float* ln1_b = (const float*)d_in[31];

    float* out0 = (float*)d_out;
    float* out1 = out0 + TH;
    float* out2 = out1 + H_DIM;
    float* out3 = out2 + NH * HS * HS;

    float* F = (float*)d_ws;
    float* xn   = F;                          // dead after mix; reused as VH
    float* rb   = F + (size_t)1 * TH;
    float* kb   = F + (size_t)2 * TH;
    float* vb   = F + (size_t)3 * TH;
    float* ab   = F + (size_t)4 * TH;
    float* wpre = F + (size_t)5 * TH;
    float* vresb= F + (size_t)6 * TH;
    float* gb   = F + (size_t)7 * TH;
    float* yb   = F + (size_t)8 * TH;
    bf16* B = (bf16*)(F + (size_t)9 * TH);
    bf16 *xrb = B, *xwb = B + (size_t)TH, *xkb = B + (size_t)2 * TH,
         *xvb = B + (size_t)3 * TH, *xab = B + (size_t)4 * TH, *xgb = B + (size_t)5 * TH;
    bf16* Wrb = B + (size_t)6 * TH;
    bf16* Wkb = Wrb + (size_t)HH;
    bf16* Wvb = Wkb + (size_t)HH;
    bf16* Wob = Wvb + (size_t)HH;
    bf16* pp = Wob + (size_t)HH;
    bf16* a1T = pp; pp += (size_t)H_DIM * 64;
    bf16* w1T = pp; pp += (size_t)H_DIM * 64;
    bf16* v1T = pp; pp += (size_t)H_DIM * 32;
    bf16* g1T = pp; pp += (size_t)H_DIM * 128;
    bf16* a2T = pp; pp += (size_t)H_DIM * 64;
    bf16* w2T = pp; pp += (size_t)H_DIM * 64;
    bf16* v2T = pp; pp += (size_t)H_DIM * 32;
    bf16* g2T = pp; pp += (size_t)H_DIM * 128;
    bf16* amid = pp; pp += (size_t)T_TOK * 64;
    bf16* wmid = pp; pp += (size_t)T_TOK * 64;
    bf16* vmid = pp; pp += (size_t)T_TOK * 32;
    bf16* gmid = pp; pp += (size_t)T_TOK * 128;
    bf16* ybig = pp; pp += (size_t)TH;

    // Packed scan records: 32 heads x 1024 t x 768 B = 24 MB, exactly
    // Wrb+Wkb+Wvb (all dead after the r/k/v GEMMs; Wob untouched).
    // VH: per-head v fp32, 8 MB, reuses xn (dead after mix).
    char* PKW = (char*)Wrb;
    float* VH = xn;

    // 1. cast big weights to bf16
    CastPar cp;
    cp.src[0] = W_r; cp.src[1] = W_k; cp.src[2] = W_v; cp.src[3] = W_o;
    cp.dst[0] = Wrb; cp.dst[1] = Wkb; cp.dst[2] = Wvb; cp.dst[3] = Wob;
    castw_kernel<<<dim3(HH / 4 / 256, 1, 4), 256, 0, stream>>>(cp);

    // 2. transpose + cast small weights
    TPar tp;
    tp.src[0] = a1; tp.dst[0] = a1T; tp.R[0] = H_DIM; tp.C[0] = 64;
    tp.src[1] = w1; tp.dst[1] = w1T; tp.R[1] = H_DIM; tp.C[1] = 64;
    tp.src[2] = v1; tp.dst[2] = v1T; tp.R[2] = H_DIM; tp.C[2] = 32;
    tp.src[3] = g1; tp.dst[3] = g1T; tp.R[3] = H_DIM; tp.C[3] = 128;
    tp.src[4] = a2; tp.dst[4] = a2T; tp.R[4] = 64;  tp.C[4] = H_DIM;
    tp.src[5] = w2; tp.dst[5] = w2T; tp.R[5] = 64;  tp.C[5] = H_DIM;
    tp.src[6] = v2; tp.dst[6] = v2T; tp.R[6] = 32;  tp.C[6] = H_DIM;
    tp.src[7] = g2; tp.dst[7] = g2T; tp.R[7] = 128; tp.C[7] = H_DIM;
    transpose_kernel<<<dim3((H_DIM * 128 + 255) / 256, 1, 8), 256, 0, stream>>>(tp);

    // 3. LayerNorm
    ln_kernel<<<dim3(T_TOK), 256, 0, stream>>>(x, ln1_w, ln1_b, xn, out1);

    // 4. token-shift mixes
    MixPar mp; mp.xn = xn; mp.state1 = state1;
    mp.mv[0] = x_r; mp.mv[1] = x_w; mp.mv[2] = x_k; mp.mv[3] = x_v; mp.mv[4] = x_a; mp.mv[5] = x_g;
    mp.out[0] = xrb; mp.out[1] = xwb; mp.out[2] = xkb; mp.out[3] = xvb; mp.out[4] = xab; mp.out[5] = xgb;
    mix_kernel<<<dim3(T_TOK), 256, 0, stream>>>(mp);

    // 5. r,k,v GEMMs (4-stage pipelined)
    BGPar bp{};
    bp.X[0] = xrb; bp.W[0] = Wrb; bp.out[0] = rb; bp.resid[0] = nullptr;
    bp.X[1] = xkb; bp.W[1] = Wkb; bp.out[1] = kb; bp.resid[1] = nullptr;
    bp.X[2] = xvb; bp.W[2] = Wvb; bp.out[2] = vb; bp.resid[2] = nullptr;
    bgemm_kernel<<<dim3(16, 8, 3), 256, 0, stream>>>(bp);

    // 6. low-rank stage 1
    GPar s1{}; s1.M = T_TOK;
    s1.X[0] = xab; s1.W[0] = a1T; s1.outB[0] = amid; s1.N[0] = 64;  s1.K[0] = H_DIM; s1.act[0] = 0;
    s1.X[1] = xwb; s1.W[1] = w1T; s1.outB[1] = wmid; s1.N[1] = 64;  s1.K[1] = H_DIM; s1.act[1] = 2;
    s1.X[2] = xvb; s1.W[2] = v1T; s1.outB[2] = vmid; s1.N[2] = 32;  s1.K[2] = H_DIM; s1.act[2] = 0;
    s1.X[3] = xgb; s1.W[3] = g1T; s1.outB[3] = gmid; s1.N[3] = 128; s1.K[3] = H_DIM; s1.act[3] = 1;
    gemm_z_kernel<<<dim3(1, 8, 4), 256, 0, stream>>>(s1);

    // 7. low-rank stage 2
    GPar s2{}; s2.M = T_TOK;
    s2.X[0] = amid; s2.W[0] = a2T; s2.outF[0] = ab;    s2.N[0] = H_DIM; s2.K[0] = 64;  s2.act[0] = 1; s2.bias[0] = a0;
    s2.X[1] = wmid; s2.W[1] = w2T; s2.outF[1] = wpre;  s2.N[1] = H_DIM; s2.K[1] = 64;  s2.act[1] = 0;
    s2.X[2] = vmid; s2.W[2] = v2T; s2.outF[2] = vresb; s2.N[2] = H_DIM; s2.K[2] = 32;  s2.act[2] = 1; s2.bias[2] = v0;
    s2.X[3] = gmid; s2.W[3] = g2T; s2.outF[3] = gb;    s2.N[3] = H_DIM; s2.K[3] = 128; s2.act[3] = 0;
    gemm_z_kernel<<<dim3(16, 8, 4), 256, 0, stream>>>(s2);

    // 8. elementwise prep (+ pack 768B records [h][t] + VH)
    prep_kernel<<<dim3(NH, T_TOK), 64, 0, stream>>>(kb, vb, vfirst, vresb, wpre, ab, rb, PKW, VH, k_k, k_a, w0);

    // 9. scan: 256 blocks x (2 consumers + 1 producer), LDS ring,
    //    prefetch+unpack pipelined across steps AND chunk boundaries
    scan_kernel<<<dim3(NH, 8), 192, 0, stream>>>(PKW, VH, state2, yb, out2);

    // 10. groupnorm + bonus + gate
    post_kernel<<<dim3(NH, T_TOK), 64, 0, stream>>>(yb, rb, kb, vb, gb, r_k, ln_x_w, ln_x_b, ybig);

    // 11. final GEMM with residual
    BGPar bo{};
    bo.X[0] = ybig; bo.W[0] = Wob; bo.out[0] = out0; bo.resid[0] = x;
    bgemm_kernel<<<dim3(16, 8, 1), 256, 0, stream>>>(bo);

    // 12. v_first passthrough
    hipMemcpyAsync(out3, (const void*)vfirst, (size_t)TH * sizeof(float),
                   hipMemcpyDeviceToDevice, stream);
}

// Round 10
// 561.356 us; speedup vs baseline: 1.0281x; 1.0281x over previous
//
#include <hip/hip_runtime.h>
#include <hip/hip_bf16.h>
#include <cstdint>
#include <cstddef>

#define T_TOK 1024
#define H_DIM 2048
#define NH 32
#define HS 64
#define TH (T_TOK * H_DIM)
#define HH (H_DIM * H_DIM)

using short8 = __attribute__((ext_vector_type(8))) short;
using f32x4  = __attribute__((ext_vector_type(4))) float;
using i32x4  = __attribute__((ext_vector_type(4))) int;
typedef __hip_bfloat16 bf16;

__device__ __forceinline__ float sigmoidf_(float x) { return 1.0f / (1.0f + expf(-x)); }

__device__ __forceinline__ float wsum64(float v) {
#pragma unroll
    for (int m = 32; m; m >>= 1) v += __shfl_xor(v, m, 64);
    return v;
}

// DPP sum over aligned 16-lane groups — pure VALU, no DS ops.
__device__ __forceinline__ float dpp_add16(float x) {
    int t;
    t = __builtin_amdgcn_update_dpp(0, __float_as_int(x), 0xB1, 0xF, 0xF, true);
    x += __int_as_float(t);
    t = __builtin_amdgcn_update_dpp(0, __float_as_int(x), 0x4E, 0xF, 0xF, true);
    x += __int_as_float(t);
    t = __builtin_amdgcn_update_dpp(0, __float_as_int(x), 0x141, 0xF, 0xF, true);
    x += __int_as_float(t);
    t = __builtin_amdgcn_update_dpp(0, __float_as_int(x), 0x140, 0xF, 0xF, true);
    x += __int_as_float(t);
    return x;
}

// ---------------- cast big weights fp32 -> bf16 ----------------
struct CastPar { const float* src[4]; bf16* dst[4]; };
__global__ __launch_bounds__(256) void castw_kernel(CastPar p) {
    int z = blockIdx.z;
    const float4* s = (const float4*)p.src[z];
    bf16* d = p.dst[z];
    int i = blockIdx.x * 256 + threadIdx.x;
    float4 v = s[i];
    int b = i * 4;
    d[b + 0] = __float2bfloat16(v.x);
    d[b + 1] = __float2bfloat16(v.y);
    d[b + 2] = __float2bfloat16(v.z);
    d[b + 3] = __float2bfloat16(v.w);
}

// ---------------- transpose + cast small weights ----------------
struct TPar { const float* src[8]; bf16* dst[8]; int R[8]; int C[8]; };
__global__ __launch_bounds__(256) void transpose_kernel(TPar p) {
    int z = blockIdx.z;
    int R = p.R[z], C = p.C[z];
    int e = blockIdx.x * 256 + threadIdx.x;
    if (e >= R * C) return;
    int r = e / C, c = e % C;
    p.dst[z][(size_t)c * R + r] = __float2bfloat16(p.src[z][e]);
}

// ---------------- LayerNorm (ln1) ----------------
__global__ __launch_bounds__(256) void ln_kernel(const float* __restrict__ x,
                                                 const float* __restrict__ w,
                                                 const float* __restrict__ b,
                                                 float* __restrict__ xn,
                                                 float* __restrict__ s1out) {
    int t = blockIdx.x, tid = threadIdx.x;
    const float* xt = x + (size_t)t * H_DIM;
    float v[8]; float s = 0.f, s2 = 0.f;
#pragma unroll
    for (int e = 0; e < 8; e++) { v[e] = xt[tid + 256 * e]; s += v[e]; s2 += v[e] * v[e]; }
    s = wsum64(s); s2 = wsum64(s2);
    __shared__ float ls[8];
    int wid = tid >> 6, ln = tid & 63;
    if (ln == 0) { ls[wid] = s; ls[4 + wid] = s2; }
    __syncthreads();
    s = ls[0] + ls[1] + ls[2] + ls[3];
    s2 = ls[4] + ls[5] + ls[6] + ls[7];
    float mu = s * (1.f / H_DIM);
    float var = s2 * (1.f / H_DIM) - mu * mu;
    float inv = rsqrtf(var + 1e-5f);
#pragma unroll
    for (int e = 0; e < 8; e++) {
        int h = tid + 256 * e;
        float o = (v[e] - mu) * inv * w[h] + b[h];
        xn[(size_t)t * H_DIM + h] = o;
        if (t == T_TOK - 1) s1out[h] = o;
    }
}

// ---------------- token-shift mixes ----------------
struct MixPar { const float* xn; const float* state1; const float* mv[6]; bf16* out[6]; };
__global__ __launch_bounds__(256) void mix_kernel(MixPar p) {
    int t = blockIdx.x, tid = threadIdx.x;
#pragma unroll
    for (int e = 0; e < 8; e++) {
        int h = tid + 256 * e;
        size_t idx = (size_t)t * H_DIM + h;
        float cur = p.xn[idx];
        float prev = (t == 0) ? p.state1[h] : p.xn[idx - H_DIM];
        float sx = prev - cur;
#pragma unroll
        for (int q = 0; q < 6; q++)
            p.out[q][idx] = __float2bfloat16(cur + p.mv[q][h] * sx);
    }
}

// ======== async global->LDS helpers (size 16 ONLY — HW-verified path) ========
typedef const __attribute__((address_space(1))) uint32_t* gp1_t;
typedef __attribute__((address_space(3))) uint32_t* lp3_t;
__device__ __forceinline__ void async16(const bf16* g, short* l) {
    __builtin_amdgcn_global_load_lds((gp1_t)g, (lp3_t)l, 16, 0, 0);
}
__device__ __forceinline__ void async16v(const void* g, void* l) {
    __builtin_amdgcn_global_load_lds((gp1_t)g, (lp3_t)l, 16, 0, 0);
}

// ======== big GEMM: 4-stage ring global_load_lds pipeline (vmcnt(12)) ========
struct BGPar { const bf16* X[4]; const bf16* W[4]; float* out[4]; const float* resid[4]; };
__global__ __launch_bounds__(256) void bgemm_kernel(BGPar p) {
    int z = blockIdx.z;
    const bf16* __restrict__ X = p.X[z];
    const bf16* __restrict__ W = p.W[z];
    float* __restrict__ out = p.out[z];
    const float* __restrict__ resid = p.resid[z];

    __shared__ short As[4][128 * 32];   // 4 stages x 8 KB
    __shared__ short Bs[4][128 * 32];   // 4 stages x 8 KB  (64 KB total)

    int m0 = blockIdx.y * 128, n0 = blockIdx.x * 128;
    int tid = threadIdx.x, lane = tid & 63, wv = tid >> 6;
    int m_off = (wv >> 1) * 64, n_off = (wv & 1) * 64;
    int lr = lane & 15, lq = lane >> 4;

    int srow = lane >> 2;
    int scol = (lane & 3) * 8;
    const bf16* Ag0 = X + (size_t)(m0 + wv * 32 + srow) * 2048 + scol;
    const bf16* Ag1 = Ag0 + (size_t)16 * 2048;
    const bf16* Bg0 = W + (size_t)(n0 + wv * 32 + srow) * 2048 + scol;
    const bf16* Bg1 = Bg0 + (size_t)16 * 2048;

    // issue stage: tile `at` (address), ring buffer `nb`
    auto issue = [&](int at, int nb) {
        int kk = at * 32;
        async16(Ag0 + kk, &As[nb][(wv * 32) * 32]);
        async16(Ag1 + kk, &As[nb][(wv * 32 + 16) * 32]);
        async16(Bg0 + kk, &Bs[nb][(wv * 32) * 32]);
        async16(Bg1 + kk, &Bs[nb][(wv * 32 + 16) * 32]);
    };

    f32x4 acc[4][4];
#pragma unroll
    for (int a = 0; a < 4; a++)
#pragma unroll
        for (int b = 0; b < 4; b++)
#pragma unroll
            for (int r = 0; r < 4; r++) acc[a][b][r] = 0.f;

    issue(0, 0); issue(1, 1); issue(2, 2);

    for (int it = 0; it < 64; it++) {
        int nt = it + 3;
        int at = nt > 63 ? 63 : nt;      // clamp address; redundant tail loads keep vmcnt uniform
        issue(at, nt & 3);               // buf (it-1)&3: consumed last iter, safe after trailing barrier
        asm volatile("s_waitcnt vmcnt(12)" ::: "memory");  // stage `it` landed; 3 stages stay in flight
        asm volatile("s_barrier" ::: "memory");            // all waves' stage-it data in LDS
        int buf = it & 3;
        short8 af[4], bfr[4];
#pragma unroll
        for (int mi = 0; mi < 4; mi++)
            af[mi] = *(const short8*)&As[buf][(m_off + mi * 16 + lr) * 32 + lq * 8];
#pragma unroll
        for (int ni = 0; ni < 4; ni++)
            bfr[ni] = *(const short8*)&Bs[buf][(n_off + ni * 16 + lr) * 32 + lq * 8];
#pragma unroll
        for (int mi = 0; mi < 4; mi++)
#pragma unroll
            for (int ni = 0; ni < 4; ni++)
                acc[mi][ni] = __builtin_amdgcn_mfma_f32_16x16x32_bf16(af[mi], bfr[ni], acc[mi][ni], 0, 0, 0);
        asm volatile("s_barrier" ::: "memory");            // buf free for overwrite next iter
    }
    asm volatile("s_waitcnt vmcnt(0)" ::: "memory");       // drain redundant tail loads

#pragma unroll
    for (int mi = 0; mi < 4; mi++)
#pragma unroll
        for (int ni = 0; ni < 4; ni++)
#pragma unroll
            for (int r = 0; r < 4; r++) {
                int rowg = m0 + m_off + mi * 16 + lq * 4 + r;
                int colg = n0 + n_off + ni * 16 + lr;
                size_t o = (size_t)rowg * 2048 + colg;
                float v = acc[mi][ni][r];
                if (resid) v += resid[o];
                out[o] = v;
            }
}

// ---------------- generic small-GEMM ----------------
#define BM 128
#define BN 128
#define BK 32
#define LDK 40

__device__ __forceinline__ void gemm_core(const bf16* __restrict__ X, const bf16* __restrict__ W,
                                          int M, int N, int K, int act,
                                          const float* __restrict__ bias,
                                          float* __restrict__ outF, bf16* __restrict__ outB) {
    __shared__ short As[BM * LDK];
    __shared__ short Bs[BN * LDK];
    int m0 = blockIdx.y * BM, n0 = blockIdx.x * BN;
    if (n0 >= N) return;
    int tid = threadIdx.x;
    int lane = tid & 63, wid = tid >> 6;
    int m_off = (wid >> 1) * 64, n_off = (wid & 1) * 64;
    int lr = lane & 15, lq = lane >> 4;

    f32x4 acc[4][4];
#pragma unroll
    for (int a = 0; a < 4; a++)
#pragma unroll
        for (int b = 0; b < 4; b++)
#pragma unroll
            for (int r = 0; r < 4; r++) acc[a][b][r] = 0.f;

    for (int k0 = 0; k0 < K; k0 += BK) {
#pragma unroll
        for (int it = 0; it < 2; it++) {
            int c = tid + it * 256;
            int r = c >> 2;
            int cc = (c & 3) * 8;
            uint4 va = *(const uint4*)(X + (size_t)(m0 + r) * K + k0 + cc);
            *(uint4*)&As[r * LDK + cc] = va;
            uint4 vb;
            if (n0 + r < N) vb = *(const uint4*)(W + (size_t)(n0 + r) * K + k0 + cc);
            else            vb = make_uint4(0u, 0u, 0u, 0u);
            *(uint4*)&Bs[r * LDK + cc] = vb;
        }
        __syncthreads();
        short8 af[4], bfr[4];
#pragma unroll
        for (int mi = 0; mi < 4; mi++)
            af[mi] = *(const short8*)&As[(m_off + mi * 16 + lr) * LDK + lq * 8];
#pragma unroll
        for (int ni = 0; ni < 4; ni++)
            bfr[ni] = *(const short8*)&Bs[(n_off + ni * 16 + lr) * LDK + lq * 8];
#pragma unroll
        for (int mi = 0; mi < 4; mi++)
#pragma unroll
            for (int ni = 0; ni < 4; ni++)
                acc[mi][ni] = __builtin_amdgcn_mfma_f32_16x16x32_bf16(af[mi], bfr[ni], acc[mi][ni], 0, 0, 0);
        __syncthreads();
    }
#pragma unroll
    for (int mi = 0; mi < 4; mi++)
#pragma unroll
        for (int ni = 0; ni < 4; ni++)
#pragma unroll
            for (int r = 0; r < 4; r++) {
                int rowg = m0 + m_off + mi * 16 + lq * 4 + r;
                int colg = n0 + n_off + ni * 16 + lr;
                if (colg < N) {
                    float v = acc[mi][ni][r];
                    if (bias) v += bias[colg];
                    if (act == 1) v = sigmoidf_(v);
                    else if (act == 2) v = tanhf(v);
                    size_t o = (size_t)rowg * N + colg;
                    if (outF) outF[o] = v;
                    else      outB[o] = __float2bfloat16(v);
                }
            }
}

struct GPar {
    const bf16* X[4]; const bf16* W[4];
    float* outF[4]; bf16* outB[4];
    const float* bias[4];
    int N[4]; int K[4]; int act[4]; int M;
};
__global__ __launch_bounds__(256) void gemm_z_kernel(GPar p) {
    int z = blockIdx.z;
    gemm_core(p.X[z], p.W[z], p.M, p.N[z], p.K[z], p.act[z], p.bias[z], p.outF[z], p.outB[z]);
}

// ---------------- elementwise prep for the scan ----------------
// Writes, per (h,t), ONE contiguous 768 B record at PKW + (h*T + t)*768:
//   bytes [0,256):   w   fp32[64]                  (precision-critical decay)
//   bytes [256,512): a|b bf16, per jb 16B = {a0..a3, b0..b3}
//   bytes [512,768): k|r bf16, per jb 16B = {k0..k3, r0..r3}
// [h][t] order makes a 16-step chunk 12288 CONTIGUOUS bytes = 12 x async16.
// v goes to VH[h][t][64] fp32 (per-head contiguous: 16-step chunk = 4 async16).
// v also still written to vb for post_kernel.
__global__ __launch_bounds__(64) void prep_kernel(float* __restrict__ k_io, float* __restrict__ v_io,
                                                  const float* __restrict__ v_first,
                                                  const float* __restrict__ vres,
                                                  const float* __restrict__ w_in,
                                                  const float* __restrict__ a_io,
                                                  const float* __restrict__ r_in,
                                                  char* __restrict__ pkw,
                                                  float* __restrict__ vh,
                                                  const float* __restrict__ k_k,
                                                  const float* __restrict__ k_a,
                                                  const float* __restrict__ w0) {
    int h = blockIdx.x, t = blockIdx.y, i = threadIdx.x;
    int hi = h * HS + i;
    size_t idx = (size_t)t * H_DIM + hi;
    float kf = k_io[idx];
    float kk = kf * k_k[hi];
    float ss = wsum64(kk * kk);
    float kkn = kk / (sqrtf(ss) + 1e-12f);
    float a = a_io[idx];
    float knew = kf * (1.f + (a - 1.f) * k_a[hi]);
    k_io[idx] = knew;                       // fp32 k kept for post_kernel
    float vv = v_io[idx];
    float vnew = vv + (v_first[idx] - vv) * vres[idx];
    v_io[idx] = vnew;
    float wfin = expf(-0.606531f * sigmoidf_(w0[hi] + w_in[idx]));

    char* rec = pkw + ((size_t)h * T_TOK + t) * 768;
    ((float*)rec)[i] = wfin;
    int sub = (i >> 2) * 8 + (i & 3);
    bf16* ab = (bf16*)(rec + 256);
    bf16* kr = (bf16*)(rec + 512);
    ab[sub]     = __float2bfloat16(-kkn);       // a_seq
    ab[sub + 4] = __float2bfloat16(kkn * a);    // b_seq
    kr[sub]     = __float2bfloat16(knew);       // k
    kr[sub + 4] = __float2bfloat16(r_in[idx]);  // r

    vh[((size_t)h * T_TOK + t) * HS + i] = vnew;
}

// ---------------- WKV7 scan: producer/consumer LDS ring ----------------
// r8 (WIN, 148->132us): one-step LDS prefetch + tree reduction. r9 (unpack
// hoist, REGRESSED 137): scan is NOT issue-bound — extra reg-copies hurt.
// Remaining ~310cy/step = chain (~60-100) + issue (~70) + ~150cy of
// PER-CHUNK overheads amortized over 8 steps: chunk-boundary serial LDS
// reload (~120cy), 3-wave barrier rendezvous, loop overhead. All scale
// 1/SC_CH. This round: SC_CH 8->16 on the EXACT r8 consumer body; ring
// 4->3 slots (48KB LDS). Producer: 16 async16/chunk (12 rec + 4 v),
// 2 chunks in flight, steady vmcnt(16). Slot ledger: consumers read
// slot c%3 at iter c; producer writes slot (c+2)%3 (data chunk
// min(c+2,63)) — disjoint from c%3 and (c+1)%3 at all times; the tail
// clamp lands chunk-63 data in the UNREAD slot, so no writer/reader
// overlap ever.
#define SC_CH 16         // steps per chunk
#define SC_SLOT 16384    // 12288 pkw + 4096 v
__global__ __launch_bounds__(192) void scan_kernel(const char* __restrict__ pkw,
                                                   const float* __restrict__ vh,
                                                   const float* __restrict__ s2in,
                                                   float* __restrict__ y,
                                                   float* __restrict__ s2out) {
    __shared__ char smem[3 * SC_SLOT];   // 48 KB
    int h = blockIdx.x, bq = blockIdx.y;
    int wid = threadIdx.x >> 6;          // 0,1 = consumers; 2 = producer
    int lane = threadIdx.x & 63;
    int hb = h * HS;

    // consumer-side geometry
    int q = bq * 2 + wid;                // valid for wid<2
    int il = lane >> 4, jb = lane & 15;
    int row = q * 4 + il;

    float S[4] = {0.f, 0.f, 0.f, 0.f};
    if (wid < 2) {
        const float* s0 = s2in + (size_t)h * HS * HS + (size_t)row * HS + (size_t)jb * 4;
        float4 t0 = *(const float4*)s0;
        S[0] = t0.x; S[1] = t0.y; S[2] = t0.z; S[3] = t0.w;
    }

    // producer: issue one chunk (16 steps, 16 x async16) into ring `slot`,
    // sourcing data chunk `cdata`
    auto issue_chunk = [&](int slot, int cdata) {
        char* lb = smem + (size_t)slot * SC_SLOT;
        const char* gp = pkw + ((size_t)h * T_TOK + (size_t)cdata * SC_CH) * 768;
        const char* gv = (const char*)vh + ((size_t)h * T_TOK + (size_t)cdata * SC_CH) * 256;
#pragma unroll
        for (int i = 0; i < 12; i++)
            async16v(gp + i * 1024 + lane * 16, lb + i * 1024);
#pragma unroll
        for (int i = 0; i < 4; i++)
            async16v(gv + i * 1024 + lane * 16, lb + 12288 + i * 1024);
    };

    if (wid == 2) {
        issue_chunk(0, 0); issue_chunk(1, 1);   // 32 ops in flight
    }

    const int NCH = T_TOK / SC_CH;   // 64 chunks
    for (int c = 0; c < NCH; c++) {
        if (wid == 2)
            asm volatile("s_waitcnt vmcnt(16)" ::: "memory");  // chunk c landed
        asm volatile("" ::: "memory");
        __builtin_amdgcn_s_barrier();
        asm volatile("" ::: "memory");
        if (wid == 2) {
            int cn = c + 2;
            if (cn > NCH - 1) cn = NCH - 1;   // redundant tail data into the unread slot
            issue_chunk((c + 2) % 3, cn);
        } else {
            const char* lb = smem + (size_t)(c % 3) * SC_SLOT;
            // software-pipelined LDS reads: step j issues j+1's reads before
            // consuming j's already-resident registers.
            f32x4 wvA = *(const f32x4*)(lb + jb * 16);
            i32x4 q0A = *(const i32x4*)(lb + 256 + jb * 16);
            i32x4 q1A = *(const i32x4*)(lb + 512 + jb * 16);
            float vA  = *(const float*)(lb + 12288 + row * 4);
#pragma unroll
            for (int j = 0; j < SC_CH; j++) {
                f32x4 wvB; i32x4 q0B, q1B; float vB;
                if (j + 1 < SC_CH) {
                    wvB = *(const f32x4*)(lb + (j + 1) * 768 + jb * 16);
                    q0B = *(const i32x4*)(lb + (j + 1) * 768 + 256 + jb * 16);
                    q1B = *(const i32x4*)(lb + (j + 1) * 768 + 512 + jb * 16);
                    vB  = *(const float*)(lb + 12288 + (j + 1) * 256 + row * 4);
                }
                int t = c * SC_CH + j;
                float af[4], bb[4], kf[4], rf[4];
                uint32_t u;
                u = (uint32_t)q0A[0]; af[0] = __uint_as_float(u << 16); af[1] = __uint_as_float(u & 0xffff0000u);
                u = (uint32_t)q0A[1]; af[2] = __uint_as_float(u << 16); af[3] = __uint_as_float(u & 0xffff0000u);
                u = (uint32_t)q0A[2]; bb[0] = __uint_as_float(u << 16); bb[1] = __uint_as_float(u & 0xffff0000u);
                u = (uint32_t)q0A[3]; bb[2] = __uint_as_float(u << 16); bb[3] = __uint_as_float(u & 0xffff0000u);
                u = (uint32_t)q1A[0]; kf[0] = __uint_as_float(u << 16); kf[1] = __uint_as_float(u & 0xffff0000u);
                u = (uint32_t)q1A[1]; kf[2] = __uint_as_float(u << 16); kf[3] = __uint_as_float(u & 0xffff0000u);
                u = (uint32_t)q1A[2]; rf[0] = __uint_as_float(u << 16); rf[1] = __uint_as_float(u & 0xffff0000u);
                u = (uint32_t)q1A[3]; rf[2] = __uint_as_float(u << 16); rf[3] = __uint_as_float(u & 0xffff0000u);
                // tree-reduced 4-elem accumulations (shorter dependent chain)
#pragma unroll
                for (int e = 0; e < 4; e++) S[e] *= wvA[e];
                float sa = fmaf(S[0], af[0], S[1] * af[1]) + fmaf(S[2], af[2], S[3] * af[3]);
                sa = dpp_add16(sa);
#pragma unroll
                for (int e = 0; e < 4; e++)
                    S[e] = fmaf(sa, bb[e], fmaf(vA, kf[e], S[e]));
                float o = fmaf(S[0], rf[0], S[1] * rf[1]) + fmaf(S[2], rf[2], S[3] * rf[3]);
                o = dpp_add16(o);
                y[(size_t)t * H_DIM + hb + row] = o;   // 16 lanes, same addr/value
                if (j + 1 < SC_CH) {
                    wvA = wvB; q0A = q0B; q1A = q1B; vA = vB;
                }
            }
        }
    }
    if (wid == 2) {
        asm volatile("s_waitcnt vmcnt(0)" ::: "memory");   // drain redundant tail before exit
    } else {
        float* so = s2out + (size_t)h * HS * HS + (size_t)row * HS + (size_t)jb * 4;
        float4 t0;
        t0.x = S[0]; t0.y = S[1]; t0.z = S[2]; t0.w = S[3];
        *(float4*)so = t0;
    }
}

// ---------------- groupnorm + bonus + gate -> bf16 ----------------
__global__ __launch_bounds__(64) void post_kernel(const float* __restrict__ y,
                                                  const float* __restrict__ r_s,
                                                  const float* __restrict__ k_s,
                                                  const float* __restrict__ v_s,
                                                  const float* __restrict__ g_s,
                                                  const float* __restrict__ r_k,
                                                  const float* __restrict__ lnw,
                                                  const float* __restrict__ lnb,
                                                  bf16* __restrict__ ybig) {
    int h = blockIdx.x, t = blockIdx.y, i = threadIdx.x;
    int hi = h * HS + i;
    size_t idx = (size_t)t * H_DIM + hi;
    float yv = y[idx];
    float mu = wsum64(yv) * (1.f / HS);
    float d = yv - mu;
    float var = wsum64(d * d) * (1.f / HS);
    float yn = d * rsqrtf(var + 0.00064f);
    float bd = wsum64(r_s[idx] * k_s[idx] * r_k[hi]);
    float val = (yn * lnw[hi] + lnb[hi] + bd * v_s[idx]) * g_s[idx];
    ybig[idx] = __float2bfloat16(val);
}

// ---------------- launcher ----------------
extern "C" void kernel_launch(void* const* d_in, const int* in_sizes, int n_in,
                              void* d_out, int out_size, void* d_ws, size_t ws_size,
                              hipStream_t stream) {
    const float* x      = (const float*)d_in[0];
    const float* state1 = (const float*)d_in[1];
    const float* state2 = (const float*)d_in[2];
    const float* vfirst = (const float*)d_in[3];
    const float* x_r = (const float*)d_in[4];
    const float* x_w = (const float*)d_in[5];
    const float* x_k = (const float*)d_in[6];
    const float* x_v = (const float*)d_in[7];
    const float* x_a = (const float*)d_in[8];
    const float* x_g = (const float*)d_in[9];
    const float* W_r = (const float*)d_in[10];
    const float* W_k = (const float*)d_in[11];
    const float* W_v = (const float*)d_in[12];
    const float* W_o = (const float*)d_in[13];
    const float* w0 = (const float*)d_in[14];
    const float* w1 = (const float*)d_in[15];
    const float* w2 = (const float*)d_in[16];
    const float* a0 = (const float*)d_in[17];
    const float* a1 = (const float*)d_in[18];
    const float* a2 = (const float*)d_in[19];
    const float* v0 = (const float*)d_in[20];
    const float* v1 = (const float*)d_in[21];
    const float* v2 = (const float*)d_in[22];
    const float* g1 = (const float*)d_in[23];
    const float* g2 = (const float*)d_in[24];
    const float* k_k = (const float*)d_in[25];
    const float* k_a = (const float*)d_in[26];
    const float* r_k = (const float*)d_in[27];
    const float* ln_x_w = (const float*)d_in[28];
    const float* ln_x_b = (const float*)d_in[29];
    const float* ln1_w = (const float*)d_in[30];
    const float* ln1_b = (const float*)d_in[31];

    float* out0 = (float*)d_out;
    float* out1 = out0 + TH;
    float* out2 = out1 + H_DIM;
    float* out3 = out2 + NH * HS * HS;

    float* F = (float*)d_ws;
    float* xn   = F;                          // dead after mix; reused as VH
    float* rb   = F + (size_t)1 * TH;
    float* kb   = F + (size_t)2 * TH;
    float* vb   = F + (size_t)3 * TH;
    float* ab   = F + (size_t)4 * TH;
    float* wpre = F + (size_t)5 * TH;
    float* vresb= F + (size_t)6 * TH;
    float* gb   = F + (size_t)7 * TH;
    float* yb   = F + (size_t)8 * TH;
    bf16* B = (bf16*)(F + (size_t)9 * TH);
    bf16 *xrb = B, *xwb = B + (size_t)TH, *xkb = B + (size_t)2 * TH,
         *xvb = B + (size_t)3 * TH, *xab = B + (size_t)4 * TH, *xgb = B + (size_t)5 * TH;
    bf16* Wrb = B + (size_t)6 * TH;
    bf16* Wkb = Wrb + (size_t)HH;
    bf16* Wvb = Wkb + (size_t)HH;
    bf16* Wob = Wvb + (size_t)HH;
    bf16* pp = Wob + (size_t)HH;
    bf16* a1T = pp; pp += (size_t)H_DIM * 64;
    bf16* w1T = pp; pp += (size_t)H_DIM * 64;
    bf16* v1T = pp; pp += (size_t)H_DIM * 32;
    bf16* g1T = pp; pp += (size_t)H_DIM * 128;
    bf16* a2T = pp; pp += (size_t)H_DIM * 64;
    bf16* w2T = pp; pp += (size_t)H_DIM * 64;
    bf16* v2T = pp; pp += (size_t)H_DIM * 32;
    bf16* g2T = pp; pp += (size_t)H_DIM * 128;
    bf16* amid = pp; pp += (size_t)T_TOK * 64;
    bf16* wmid = pp; pp += (size_t)T_TOK * 64;
    bf16* vmid = pp; pp += (size_t)T_TOK * 32;
    bf16* gmid = pp; pp += (size_t)T_TOK * 128;
    bf16* ybig = pp; pp += (size_t)TH;

    // Packed scan records: 32 heads x 1024 t x 768 B = 24 MB, exactly
    // Wrb+Wkb+Wvb (all dead after the r/k/v GEMMs; Wob untouched).
    // VH: per-head v fp32, 8 MB, reuses xn (dead after mix).
    char* PKW = (char*)Wrb;
    float* VH = xn;

    // 1. cast big weights to bf16
    CastPar cp;
    cp.src[0] = W_r; cp.src[1] = W_k; cp.src[2] = W_v; cp.src[3] = W_o;
    cp.dst[0] = Wrb; cp.dst[1] = Wkb; cp.dst[2] = Wvb; cp.dst[3] = Wob;
    castw_kernel<<<dim3(HH / 4 / 256, 1, 4), 256, 0, stream>>>(cp);

    // 2. transpose + cast small weights
    TPar tp;
    tp.src[0] = a1; tp.dst[0] = a1T; tp.R[0] = H_DIM; tp.C[0] = 64;
    tp.src[1] = w1; tp.dst[1] = w1T; tp.R[1] = H_DIM; tp.C[1] = 64;
    tp.src[2] = v1; tp.dst[2] = v1T; tp.R[2] = H_DIM; tp.C[2] = 32;
    tp.src[3] = g1; tp.dst[3] = g1T; tp.R[3] = H_DIM; tp.C[3] = 128;
    tp.src[4] = a2; tp.dst[4] = a2T; tp.R[4] = 64;  tp.C[4] = H_DIM;
    tp.src[5] = w2; tp.dst[5] = w2T; tp.R[5] = 64;  tp.C[5] = H_DIM;
    tp.src[6] = v2; tp.dst[6] = v2T; tp.R[6] = 32;  tp.C[6] = H_DIM;
    tp.src[7] = g2; tp.dst[7] = g2T; tp.R[7] = 128; tp.C[7] = H_DIM;
    transpose_kernel<<<dim3((H_DIM * 128 + 255) / 256, 1, 8), 256, 0, stream>>>(tp);

    // 3. LayerNorm
    ln_kernel<<<dim3(T_TOK), 256, 0, stream>>>(x, ln1_w, ln1_b, xn, out1);

    // 4. token-shift mixes
    MixPar mp; mp.xn = xn; mp.state1 = state1;
    mp.mv[0] = x_r; mp.mv[1] = x_w; mp.mv[2] = x_k; mp.mv[3] = x_v; mp.mv[4] = x_a; mp.mv[5] = x_g;
    mp.out[0] = xrb; mp.out[1] = xwb; mp.out[2] = xkb; mp.out[3] = xvb; mp.out[4] = xab; mp.out[5] = xgb;
    mix_kernel<<<dim3(T_TOK), 256, 0, stream>>>(mp);

    // 5. r,k,v GEMMs (4-stage pipelined)
    BGPar bp{};
    bp.X[0] = xrb; bp.W[0] = Wrb; bp.out[0] = rb; bp.resid[0] = nullptr;
    bp.X[1] = xkb; bp.W[1] = Wkb; bp.out[1] = kb; bp.resid[1] = nullptr;
    bp.X[2] = xvb; bp.W[2] = Wvb; bp.out[2] = vb; bp.resid[2] = nullptr;
    bgemm_kernel<<<dim3(16, 8, 3), 256, 0, stream>>>(bp);

    // 6. low-rank stage 1
    GPar s1{}; s1.M = T_TOK;
    s1.X[0] = xab; s1.W[0] = a1T; s1.outB[0] = amid; s1.N[0] = 64;  s1.K[0] = H_DIM; s1.act[0] = 0;
    s1.X[1] = xwb; s1.W[1] = w1T; s1.outB[1] = wmid; s1.N[1] = 64;  s1.K[1] = H_DIM; s1.act[1] = 2;
    s1.X[2] = xvb; s1.W[2] = v1T; s1.outB[2] = vmid; s1.N[2] = 32;  s1.K[2] = H_DIM; s1.act[2] = 0;
    s1.X[3] = xgb; s1.W[3] = g1T; s1.outB[3] = gmid; s1.N[3] = 128; s1.K[3] = H_DIM; s1.act[3] = 1;
    gemm_z_kernel<<<dim3(1, 8, 4), 256, 0, stream>>>(s1);

    // 7. low-rank stage 2
    GPar s2{}; s2.M = T_TOK;
    s2.X[0] = amid; s2.W[0] = a2T; s2.outF[0] = ab;    s2.N[0] = H_DIM; s2.K[0] = 64;  s2.act[0] = 1; s2.bias[0] = a0;
    s2.X[1] = wmid; s2.W[1] = w2T; s2.outF[1] = wpre;  s2.N[1] = H_DIM; s2.K[1] = 64;  s2.act[1] = 0;
    s2.X[2] = vmid; s2.W[2] = v2T; s2.outF[2] = vresb; s2.N[2] = H_DIM; s2.K[2] = 32;  s2.act[2] = 1; s2.bias[2] = v0;
    s2.X[3] = gmid; s2.W[3] = g2T; s2.outF[3] = gb;    s2.N[3] = H_DIM; s2.K[3] = 128; s2.act[3] = 0;
    gemm_z_kernel<<<dim3(16, 8, 4), 256, 0, stream>>>(s2);

    // 8. elementwise prep (+ pack 768B records [h][t] + VH)
    prep_kernel<<<dim3(NH, T_TOK), 64, 0, stream>>>(kb, vb, vfirst, vresb, wpre, ab, rb, PKW, VH, k_k, k_a, w0);

    // 9. scan: 256 blocks x (2 consumers + 1 producer), 3-slot LDS ring,
    //    16-step chunks, pipelined reads
    scan_kernel<<<dim3(NH, 8), 192, 0, stream>>>(PKW, VH, state2, yb, out2);

    // 10. groupnorm + bonus + gate
    post_kernel<<<dim3(NH, T_TOK), 64, 0, stream>>>(yb, rb, kb, vb, gb, r_k, ln_x_w, ln_x_b, ybig);

    // 11. final GEMM with residual
    BGPar bo{};
    bo.X[0] = ybig; bo.W[0] = Wob; bo.out[0] = out0; bo.resid[0] = x;
    bgemm_kernel<<<dim3(16, 8, 1), 256, 0, stream>>>(bo);

    // 12. v_first passthrough
    hipMemcpyAsync(out3, (const void*)vfirst, (size_t)TH * sizeof(float),
                   hipMemcpyDeviceToDevice, stream);
}